// Round 10
// baseline (850.706 us; speedup 1.0000x reference)
//
#include <hip/hip_runtime.h>

#define T_ 1024
#define B_ 4
#define D_ 1024
#define H_ 16
#define HD_ 64
#define M_ (T_ * B_)  // 4096
#define NBLK 512

typedef _Float16 f16;
typedef f16 f16x8 __attribute__((ext_vector_type(8)));
typedef f16 f16x4 __attribute__((ext_vector_type(4)));
typedef float f32x4 __attribute__((ext_vector_type(4)));

#define QSCALE 0.18033688011112042f  // 0.125 * log2(e), folded into q

__device__ __forceinline__ void gl2lds16(const void* g, void* l) {
  __builtin_amdgcn_global_load_lds(
      (const __attribute__((address_space(1))) void*)g,
      (__attribute__((address_space(3))) void*)l, 16, 0, 0);
}

// device-scope sense-reversing grid barrier (cnt/gen zeroed by memset per launch)
__device__ __forceinline__ void gbar(unsigned* cnt, unsigned* gen) {
  __syncthreads();
  if (threadIdx.x == 0) {
    unsigned g = __hip_atomic_load(gen, __ATOMIC_RELAXED, __HIP_MEMORY_SCOPE_AGENT);
    __threadfence();  // release prior global writes to device scope
    unsigned a = __hip_atomic_fetch_add(cnt, 1u, __ATOMIC_ACQ_REL, __HIP_MEMORY_SCOPE_AGENT);
    if (a == NBLK - 1) {
      __hip_atomic_store(cnt, 0u, __ATOMIC_RELAXED, __HIP_MEMORY_SCOPE_AGENT);
      __hip_atomic_fetch_add(gen, 1u, __ATOMIC_RELEASE, __HIP_MEMORY_SCOPE_AGENT);
    } else {
      while (__hip_atomic_load(gen, __ATOMIC_ACQUIRE, __HIP_MEMORY_SCOPE_AGENT) == g)
        __builtin_amdgcn_s_sleep(2);
    }
    __threadfence();  // acquire
  }
  __syncthreads();
}

struct MegaArgs {
  const float* x;
  const float* w[5];    // Wq,Wk,Wv,Wo,Wl
  const float* b3[3];   // bq,bk,bv
  const float* bo;
  const float* bl;
  const float *g1, *b1, *g2, *b2;
  f16* xb;
  f16* wd[5];           // wqkv(+0,+1M,+2M), wob, wlb
  float* bqkv;
  f16 *qb, *kb, *vb, *ctxb, *att, *hbuf;
  float* out;
  unsigned* bar;        // [0]=cnt, [1]=gen
};

// ---------------------------------------------------------------- stage: prep
__device__ __forceinline__ void prep_stage(const MegaArgs& A, int gtid) {
  constexpr int XCH = 1 << 20;   // x float4-chunks (4M elems)
  constexpr int WCH = 1 << 18;   // per-weight chunks (1M elems)
  constexpr int NCH = XCH + 5 * WCH;
#pragma unroll 1
  for (int i = gtid; i < NCH; i += NBLK * 256) {
    const float4* s;
    f16* d;
    int off;
    if (i < XCH) {
      s = (const float4*)A.x; d = A.xb; off = i;
    } else {
      const int wi = i - XCH;
      const int a = wi >> 18;
      off = wi & (WCH - 1);
      s = (const float4*)A.w[a];
      d = A.wd[a];
    }
    float4 v = s[off];
    f16x4 o = {(f16)v.x, (f16)v.y, (f16)v.z, (f16)v.w};
    *(f16x4*)(d + off * 4) = o;
  }
  if (gtid < 768) {  // concat 3 qkv biases -> bqkv[3072]
    const int j = gtid >> 8, t = gtid & 255;
    ((float4*)(A.bqkv + j * 1024))[t] = ((const float4*)A.b3[j])[t];
  }
}

// ---------------------------------------------------------------- stage: fused QKV GEMM (128x128, BK=32)
__device__ __forceinline__ void qkv_stage(const MegaArgs& A, char* smem, int vt, int tid) {
  constexpr int K = D_, BK = 32;
  f16* As = (f16*)smem;            // 8KB
  f16* Bs = (f16*)(smem + 8192);   // 8KB
  const int lane = tid & 63;
  const int quad = lane >> 4, l16 = lane & 15;
  const int m0 = (vt / 24) * 128, n0 = (vt % 24) * 128;
  const int wave = tid >> 6;
  const int wm = (wave >> 1) * 64, wn = (wave & 1) * 64;
  const f16* Ap = A.xb;
  const f16* Wp = A.wd[0];  // wqkv base [3072, K]
  f32x4 acc[4][4] = {};
  for (int kt = 0; kt < K / BK; ++kt) {
    __syncthreads();
    const int kb = kt * BK;
#pragma unroll
    for (int i = 0; i < 2; ++i) {
      const int c = i * 256 + tid;
      const int row = c >> 2, col8 = (c & 3) * 8;
      const int ldsbase = (i * 256 + (tid & ~63)) * 8;
      gl2lds16(Ap + (size_t)(m0 + row) * K + kb + col8, &As[ldsbase]);
      gl2lds16(Wp + (size_t)(n0 + row) * K + kb + col8, &Bs[ldsbase]);
    }
    __syncthreads();
    f16x8 af[4], bf[4];
#pragma unroll
    for (int i = 0; i < 4; ++i)
      af[i] = *(const f16x8*)&As[(wm + i * 16 + l16) * BK + quad * 8];
#pragma unroll
    for (int j = 0; j < 4; ++j)
      bf[j] = *(const f16x8*)&Bs[(wn + j * 16 + l16) * BK + quad * 8];
#pragma unroll
    for (int i = 0; i < 4; ++i)
#pragma unroll
      for (int j = 0; j < 4; ++j)
        acc[i][j] = __builtin_amdgcn_mfma_f32_16x16x32_f16(af[i], bf[j], acc[i][j], 0, 0, 0);
  }
  const int which = n0 >> 10;  // 0=q 1=k 2=v
  f16* outp = which == 0 ? A.qb : (which == 1 ? A.kb : A.vb);
  const float sc = which == 0 ? QSCALE : 1.0f;
#pragma unroll
  for (int j = 0; j < 4; ++j) {
    const int n = n0 + wn + j * 16 + l16;
    const float bn = A.bqkv[n];
    const int nl = n & 1023;
    const int hh = nl >> 6, d = nl & 63;
#pragma unroll
    for (int i = 0; i < 4; ++i) {
#pragma unroll
      for (int r = 0; r < 4; ++r) {
        const int m = m0 + wm + i * 16 + quad * 4 + r;
        const float v = (acc[i][j][r] + bn) * sc;
        const int t = m >> 2, bb = m & 3;  // m = t*B + b
        if (which < 2)
          outp[((size_t)(bb * H_ + hh) * T_ + t) * HD_ + d] = (f16)v;
        else
          outp[((size_t)(bb * H_ + hh) * HD_ + d) * T_ + t] = (f16)v;
      }
    }
  }
}

// ---------------------------------------------------------------- stage: attention
// LDS: Ks[0,16K) Vs[16K,32K); P-relayout buffer aliases Ks[0,4.5K) during PV
// (extra __syncthreads separates the Ks-read phase from the alias writes).
__device__ __forceinline__ void attn_stage(const MegaArgs& A, char* smem, int vt, int tid) {
  constexpr int SK = 128;
  constexpr int NT = T_ / SK;
  f16* Ks = (f16*)smem;               // 16KB
  f16* Vs = (f16*)(smem + 16384);     // 16KB
  f16* Psb = (f16*)smem;              // aliases Ks (dead during PV)
  const int wave = tid >> 6, lane = tid & 63;
  const int quad = lane >> 4, l16 = lane & 15;
  const int bh = vt & 63;             // same-XCD for all 8 q-blocks of a bh
  const int b = bh >> 4, h = bh & 15;
  const int q0 = (vt >> 6) * 128;
  const f16* Qbh = A.qb + ((size_t)bh * T_ + q0 + wave * 32) * HD_;
  const f16* Kbh = A.kb + (size_t)bh * T_ * HD_;
  const f16* Vbh = A.vb + (size_t)bh * HD_ * T_;

  f16x8 qf[2][2];
#pragma unroll
  for (int c = 0; c < 2; ++c) {
    qf[c][0] = *(const f16x8*)&Qbh[(c * 16 + l16) * HD_ + quad * 8];
    qf[c][1] = *(const f16x8*)&Qbh[(c * 16 + l16) * HD_ + 32 + quad * 8];
  }

  const f16* kq[4];
  const f16* vq[4];
  int lds_o[4];
#pragma unroll
  for (int it = 0; it < 4; ++it) {
    const int n = wave * 256 + it * 64 + lane;
    const int s = n >> 3, cp = n & 7, cl = cp ^ (s & 7);
    kq[it] = Kbh + (size_t)s * HD_ + cl * 8;
    const int d = n >> 4, cp2 = n & 15, cl2 = cp2 ^ (d & 7);
    vq[it] = Vbh + (size_t)d * T_ + cl2 * 8;
    lds_o[it] = (wave * 256 + it * 64) * 8;
  }

  f32x4 O[4][2] = {};
  float lsum[2] = {0.f, 0.f};
  const int sw = l16 & 7;

  for (int kt = 0; kt < NT; ++kt) {
    __syncthreads();  // prior-iteration readers (and Psb writers) done
#pragma unroll
    for (int it = 0; it < 4; ++it) {
      gl2lds16(kq[it], &Ks[lds_o[it]]);
      kq[it] += SK * HD_;
    }
#pragma unroll
    for (int it = 0; it < 4; ++it) {
      gl2lds16(vq[it], &Vs[lds_o[it]]);
      vq[it] += SK;
    }
    __syncthreads();  // staging complete

    float st[8][2][4];
#pragma unroll
    for (int s = 0; s < 8; ++s) {
      const int row = s * 16 + l16;
      const f16x8 ka = *(const f16x8*)&Ks[row * HD_ + (quad ^ sw) * 8];
      const f16x8 kb = *(const f16x8*)&Ks[row * HD_ + ((4 + quad) ^ sw) * 8];
#pragma unroll
      for (int c = 0; c < 2; ++c) {
        f32x4 a = {};
        a = __builtin_amdgcn_mfma_f32_16x16x32_f16(ka, qf[c][0], a, 0, 0, 0);
        a = __builtin_amdgcn_mfma_f32_16x16x32_f16(kb, qf[c][1], a, 0, 0, 0);
#pragma unroll
        for (int r = 0; r < 4; ++r) {
          st[s][c][r] = exp2f(a[r]);
          lsum[c] += st[s][c][r];
        }
      }
    }
    __syncthreads();  // all waves done reading Ks; Psb alias now safe

#pragma unroll
    for (int cI = 0; cI < 4; ++cI) {
#pragma unroll
      for (int c = 0; c < 2; ++c) {
        f16* pw = &Psb[wave * 16 * 36];
        f16x4 w0, w1;
#pragma unroll
        for (int r = 0; r < 4; ++r) {
          w0[r] = (f16)st[2 * cI][c][r];
          w1[r] = (f16)st[2 * cI + 1][c][r];
        }
        *(f16x4*)&pw[l16 * 36 + quad * 4] = w0;
        *(f16x4*)&pw[l16 * 36 + 16 + quad * 4] = w1;
        const f16x8 pf = *(const f16x8*)&pw[l16 * 36 + quad * 8];
#pragma unroll
        for (int dt = 0; dt < 4; ++dt) {
          const int d = dt * 16 + l16;
          const f16x8 vf = *(const f16x8*)&Vs[d * SK + (((cI * 4 + quad) ^ sw) * 8)];
          O[dt][c] = __builtin_amdgcn_mfma_f32_16x16x32_f16(vf, pf, O[dt][c], 0, 0, 0);
        }
      }
    }
  }

#pragma unroll
  for (int c = 0; c < 2; ++c) {
    float l = lsum[c];
    l += __shfl_xor(l, 16, 64);
    l += __shfl_xor(l, 32, 64);
    const float linv = 1.f / l;
    const int t = q0 + wave * 32 + c * 16 + l16;
#pragma unroll
    for (int dt = 0; dt < 4; ++dt) {
      f16x4 ov;
#pragma unroll
      for (int r = 0; r < 4; ++r) ov[r] = (f16)(O[dt][c][r] * linv);
      *(f16x4*)&A.ctxb[((size_t)t * B_ + b) * D_ + h * HD_ + dt * 16 + quad * 4] = ov;
    }
  }
}

// ---------------------------------------------------------------- stage: GEMM 128x64 (BK=32) + residual
__device__ __forceinline__ void gemm_stage(const f16* __restrict__ Ap,
                                           const f16* __restrict__ Wp,
                                           const float* __restrict__ bias,
                                           const f16* __restrict__ res,
                                           f16* __restrict__ out,
                                           char* smem, int vt, int tid) {
  constexpr int K = D_, BK = 32;
  f16* As = (f16*)smem;            // 8KB
  f16* Bs = (f16*)(smem + 8192);   // 4KB
  const int lane = tid & 63;
  const int quad = lane >> 4, l16 = lane & 15;
  const int m0 = (vt / 16) * 128, n0 = (vt % 16) * 64;
  const int wave = tid >> 6;
  const int wm = (wave >> 1) * 64, wn = (wave & 1) * 32;
  f32x4 acc[4][2] = {};
  for (int kt = 0; kt < K / BK; ++kt) {
    __syncthreads();
    const int kb = kt * BK;
#pragma unroll
    for (int i = 0; i < 2; ++i) {
      const int c = i * 256 + tid;
      const int row = c >> 2, col8 = (c & 3) * 8;
      const int ldsbase = (i * 256 + (tid & ~63)) * 8;
      gl2lds16(Ap + (size_t)(m0 + row) * K + kb + col8, &As[ldsbase]);
    }
    {
      const int row = tid >> 2, col8 = (tid & 3) * 8;
      const int ldsbase = (tid & ~63) * 8;
      gl2lds16(Wp + (size_t)(n0 + row) * K + kb + col8, &Bs[ldsbase]);
    }
    __syncthreads();
    f16x8 af[4], bf[2];
#pragma unroll
    for (int i = 0; i < 4; ++i)
      af[i] = *(const f16x8*)&As[(wm + i * 16 + l16) * BK + quad * 8];
#pragma unroll
    for (int j = 0; j < 2; ++j)
      bf[j] = *(const f16x8*)&Bs[(wn + j * 16 + l16) * BK + quad * 8];
#pragma unroll
    for (int i = 0; i < 4; ++i)
#pragma unroll
      for (int j = 0; j < 2; ++j)
        acc[i][j] = __builtin_amdgcn_mfma_f32_16x16x32_f16(af[i], bf[j], acc[i][j], 0, 0, 0);
  }
#pragma unroll
  for (int j = 0; j < 2; ++j) {
    const int n = n0 + wn + j * 16 + l16;
    const float bn = bias[n];
#pragma unroll
    for (int i = 0; i < 4; ++i) {
      const int m = m0 + wm + i * 16 + quad * 4;
#pragma unroll
      for (int r = 0; r < 4; ++r) {
        const float v = acc[i][j][r] + bn + (float)res[(size_t)(m + r) * D_ + n];
        out[(size_t)(m + r) * D_ + n] = (f16)v;
      }
    }
  }
}

// ---------------------------------------------------------------- stage: LayerNorm (one row)
__device__ __forceinline__ void lnorm_stage(const f16* __restrict__ a,
                                            const float* __restrict__ g,
                                            const float* __restrict__ bb,
                                            f16* __restrict__ outh,
                                            float* __restrict__ outf,
                                            char* smem, int row, int tid) {
  float* sc = (float*)smem;
  const size_t base = (size_t)row * D_;
  f16x4 va = *(const f16x4*)&a[base + tid * 4];
  float x0 = (float)va[0], x1 = (float)va[1], x2 = (float)va[2], x3 = (float)va[3];
  float s = x0 + x1 + x2 + x3;
  float sq = x0 * x0 + x1 * x1 + x2 * x2 + x3 * x3;
#pragma unroll
  for (int off = 32; off; off >>= 1) {
    s += __shfl_down(s, off, 64);
    sq += __shfl_down(sq, off, 64);
  }
  if ((tid & 63) == 0) { sc[tid >> 6] = s; sc[8 + (tid >> 6)] = sq; }
  __syncthreads();
  if (tid == 0) {
    float S = sc[0] + sc[1] + sc[2] + sc[3];
    float Qq = sc[8] + sc[9] + sc[10] + sc[11];
    float mean = S / D_;
    float var = Qq / D_ - mean * mean;
    sc[16] = mean;
    sc[17] = rsqrtf(var + 1e-5f);
  }
  __syncthreads();
  const float mean = sc[16], rstd = sc[17];
  __syncthreads();  // protect sc before next row's writes
  float4 vg = *(const float4*)&g[tid * 4];
  float4 vb = *(const float4*)&bb[tid * 4];
  float y0 = (x0 - mean) * rstd * vg.x + vb.x;
  float y1 = (x1 - mean) * rstd * vg.y + vb.y;
  float y2 = (x2 - mean) * rstd * vg.z + vb.z;
  float y3 = (x3 - mean) * rstd * vg.w + vb.w;
  if (outh) {
    f16x4 o = {(f16)y0, (f16)y1, (f16)y2, (f16)y3};
    *(f16x4*)&outh[base + tid * 4] = o;
  }
  if (outf)
    *(float4*)&outf[base + tid * 4] = make_float4(y0, y1, y2, y3);
}

// ---------------------------------------------------------------- mega kernel
// 512 blocks x 256 threads. Co-residency by construction: LDS 32768 (<=160K/4),
// __launch_bounds__(256,2) caps VGPR<=256 -> 2 waves/SIMD -> 2 blocks/CU -> 512.
__global__ __launch_bounds__(256, 2) void mega(MegaArgs A) {
  __shared__ __align__(16) char smem[32768];
  const int bid = blockIdx.x, tid = threadIdx.x;
  const int gtid = bid * 256 + tid;
  unsigned* cnt = A.bar;
  unsigned* gen = A.bar + 1;

  prep_stage(A, gtid);
  gbar(cnt, gen);

#pragma unroll 1
  for (int vt = bid; vt < 768; vt += NBLK) qkv_stage(A, smem, vt, tid);
  gbar(cnt, gen);

  attn_stage(A, smem, bid, tid);
  gbar(cnt, gen);

  gemm_stage(A.ctxb, A.wd[3], A.bo, A.xb, A.att, smem, bid, tid);  // Wo + x
  gbar(cnt, gen);

#pragma unroll 1
  for (int r = bid * 8; r < bid * 8 + 8; ++r)
    lnorm_stage(A.att, A.g1, A.b1, A.hbuf, nullptr, smem, r, tid);
  gbar(cnt, gen);

  gemm_stage(A.hbuf, A.wd[4], A.bl, A.hbuf, A.att, smem, bid, tid);  // Wl + h
  gbar(cnt, gen);

#pragma unroll 1
  for (int r = bid * 8; r < bid * 8 + 8; ++r)
    lnorm_stage(A.att, A.g2, A.b2, nullptr, A.out, smem, r, tid);
}

// ---------------------------------------------------------------- launch
extern "C" void kernel_launch(void* const* d_in, const int* in_sizes, int n_in,
                              void* d_out, int out_size, void* d_ws, size_t ws_size,
                              hipStream_t stream) {
  char* ws = (char*)d_ws;
  const size_t MB = 1 << 20;
  f16*   xb   = (f16*)(ws + 0 * MB);    // 8MB (stays alive as Wo residual)
  f16*   wqkv = (f16*)(ws + 8 * MB);    // 6MB
  f16*   wob  = (f16*)(ws + 14 * MB);   // 2MB
  f16*   wlb  = (f16*)(ws + 16 * MB);   // 2MB
  float* bqkv = (float*)(ws + 18 * MB); // 12KB
  f16*   qb   = (f16*)(ws + 19 * MB);   // 8MB -> att after attn
  f16*   kb   = (f16*)(ws + 27 * MB);   // 8MB -> hbuf after attn
  f16*   vb   = (f16*)(ws + 35 * MB);   // 8MB
  f16*   ctxb = (f16*)(ws + 43 * MB);   // 8MB
  unsigned* bar = (unsigned*)(ws + 51 * MB);

  MegaArgs ma;
  ma.x = (const float*)d_in[0];
  ma.w[0] = (const float*)d_in[1];   // Wq
  ma.b3[0] = (const float*)d_in[2];  // bq
  ma.w[1] = (const float*)d_in[3];   // Wk
  ma.b3[1] = (const float*)d_in[4];  // bk
  ma.w[2] = (const float*)d_in[5];   // Wv
  ma.b3[2] = (const float*)d_in[6];  // bv
  ma.w[3] = (const float*)d_in[7];   // Wo
  ma.bo = (const float*)d_in[8];
  ma.w[4] = (const float*)d_in[9];   // Wl
  ma.bl = (const float*)d_in[10];
  ma.g1 = (const float*)d_in[11];
  ma.b1 = (const float*)d_in[12];
  ma.g2 = (const float*)d_in[13];
  ma.b2 = (const float*)d_in[14];
  ma.xb = xb;
  ma.wd[0] = wqkv;
  ma.wd[1] = wqkv + D_ * D_;
  ma.wd[2] = wqkv + 2 * D_ * D_;
  ma.wd[3] = wob;
  ma.wd[4] = wlb;
  ma.bqkv = bqkv;
  ma.qb = qb; ma.kb = kb; ma.vb = vb; ma.ctxb = ctxb;
  ma.att = qb;    // qb dead after attn
  ma.hbuf = kb;   // kb dead after attn
  ma.out = (float*)d_out;
  ma.bar = bar;

  hipMemsetAsync(bar, 0, 128, stream);
  mega<<<NBLK, 256, 0, stream>>>(ma);
}

// Round 11
// 642.773 us; speedup vs baseline: 1.3235x; 1.3235x over previous
//
#include <hip/hip_runtime.h>

#define T_ 1024
#define B_ 4
#define D_ 1024
#define H_ 16
#define HD_ 64
#define M_ (T_ * B_)  // 4096
#define NBLK 512

typedef _Float16 f16;
typedef f16 f16x8 __attribute__((ext_vector_type(8)));
typedef f16 f16x4 __attribute__((ext_vector_type(4)));
typedef float f32x4 __attribute__((ext_vector_type(4)));

#define QSCALE 0.18033688011112042f  // 0.125 * log2(e), folded into q

__device__ __forceinline__ void gl2lds16(const void* g, void* l) {
  __builtin_amdgcn_global_load_lds(
      (const __attribute__((address_space(1))) void*)g,
      (__attribute__((address_space(3))) void*)l, 16, 0, 0);
}

// device-scope sense-reversing grid barrier (cnt/gen zeroed by memset per launch).
// CRITICAL (R10 lesson): poll with RELAXED, not ACQUIRE — an agent-scope ACQUIRE
// load invalidates the XCD's L1+L2 every iteration, poisoning all co-resident
// blocks' caches (measured: HBM BW collapsed 1.4TB/s -> 325GB/s). Relaxed
// agent-scope atomic loads still reach the coherence point (updates visible);
// one __threadfence() after exit provides the acquire.
__device__ __forceinline__ void gbar(unsigned* cnt, unsigned* gen) {
  __syncthreads();
  if (threadIdx.x == 0) {
    unsigned g = __hip_atomic_load(gen, __ATOMIC_RELAXED, __HIP_MEMORY_SCOPE_AGENT);
    // ACQ_REL RMW = release of all prior global writes (L2 writeback) + acquire
    unsigned a = __hip_atomic_fetch_add(cnt, 1u, __ATOMIC_ACQ_REL, __HIP_MEMORY_SCOPE_AGENT);
    if (a == NBLK - 1) {
      __hip_atomic_store(cnt, 0u, __ATOMIC_RELAXED, __HIP_MEMORY_SCOPE_AGENT);
      __hip_atomic_fetch_add(gen, 1u, __ATOMIC_RELEASE, __HIP_MEMORY_SCOPE_AGENT);
    } else {
      while (__hip_atomic_load(gen, __ATOMIC_RELAXED, __HIP_MEMORY_SCOPE_AGENT) == g)
        __builtin_amdgcn_s_sleep(32);  // ~2048 cyc between polls
    }
    __threadfence();  // single acquire: invalidate stale caches ONCE
  }
  __syncthreads();
}

struct MegaArgs {
  const float* x;
  const float* w[5];    // Wq,Wk,Wv,Wo,Wl
  const float* b3[3];   // bq,bk,bv
  const float* bo;
  const float* bl;
  const float *g1, *b1, *g2, *b2;
  f16* xb;
  f16* wd[5];           // wqkv(+0,+1M,+2M), wob, wlb
  float* bqkv;
  f16 *qb, *kb, *vb, *ctxb, *att, *hbuf;
  float* out;
  unsigned* bar;        // [0]=cnt, [1]=gen
};

// ---------------------------------------------------------------- stage: prep
__device__ __forceinline__ void prep_stage(const MegaArgs& A, int gtid) {
  constexpr int XCH = 1 << 20;   // x float4-chunks (4M elems)
  constexpr int WCH = 1 << 18;   // per-weight chunks (1M elems)
  constexpr int NCH = XCH + 5 * WCH;
#pragma unroll 1
  for (int i = gtid; i < NCH; i += NBLK * 256) {
    const float4* s;
    f16* d;
    int off;
    if (i < XCH) {
      s = (const float4*)A.x; d = A.xb; off = i;
    } else {
      const int wi = i - XCH;
      const int a = wi >> 18;
      off = wi & (WCH - 1);
      s = (const float4*)A.w[a];
      d = A.wd[a];
    }
    float4 v = s[off];
    f16x4 o = {(f16)v.x, (f16)v.y, (f16)v.z, (f16)v.w};
    *(f16x4*)(d + off * 4) = o;
  }
  if (gtid < 768) {  // concat 3 qkv biases -> bqkv[3072]
    const int j = gtid >> 8, t = gtid & 255;
    ((float4*)(A.bqkv + j * 1024))[t] = ((const float4*)A.b3[j])[t];
  }
}

// ---------------------------------------------------------------- stage: fused QKV GEMM (128x128, BK=32)
__device__ __forceinline__ void qkv_stage(const MegaArgs& A, char* smem, int vt, int tid) {
  constexpr int K = D_, BK = 32;
  f16* As = (f16*)smem;            // 8KB
  f16* Bs = (f16*)(smem + 8192);   // 8KB
  const int lane = tid & 63;
  const int quad = lane >> 4, l16 = lane & 15;
  const int m0 = (vt / 24) * 128, n0 = (vt % 24) * 128;
  const int wave = tid >> 6;
  const int wm = (wave >> 1) * 64, wn = (wave & 1) * 64;
  const f16* Ap = A.xb;
  const f16* Wp = A.wd[0];  // wqkv base [3072, K]
  f32x4 acc[4][4] = {};
  for (int kt = 0; kt < K / BK; ++kt) {
    __syncthreads();
    const int kb = kt * BK;
#pragma unroll
    for (int i = 0; i < 2; ++i) {
      const int c = i * 256 + tid;
      const int row = c >> 2, col8 = (c & 3) * 8;
      const int ldsbase = (i * 256 + (tid & ~63)) * 8;
      gl2lds16(Ap + (size_t)(m0 + row) * K + kb + col8, &As[ldsbase]);
      gl2lds16(Wp + (size_t)(n0 + row) * K + kb + col8, &Bs[ldsbase]);
    }
    __syncthreads();
    f16x8 af[4], bf[4];
#pragma unroll
    for (int i = 0; i < 4; ++i)
      af[i] = *(const f16x8*)&As[(wm + i * 16 + l16) * BK + quad * 8];
#pragma unroll
    for (int j = 0; j < 4; ++j)
      bf[j] = *(const f16x8*)&Bs[(wn + j * 16 + l16) * BK + quad * 8];
#pragma unroll
    for (int i = 0; i < 4; ++i)
#pragma unroll
      for (int j = 0; j < 4; ++j)
        acc[i][j] = __builtin_amdgcn_mfma_f32_16x16x32_f16(af[i], bf[j], acc[i][j], 0, 0, 0);
  }
  const int which = n0 >> 10;  // 0=q 1=k 2=v
  f16* outp = which == 0 ? A.qb : (which == 1 ? A.kb : A.vb);
  const float sc = which == 0 ? QSCALE : 1.0f;
#pragma unroll
  for (int j = 0; j < 4; ++j) {
    const int n = n0 + wn + j * 16 + l16;
    const float bn = A.bqkv[n];
    const int nl = n & 1023;
    const int hh = nl >> 6, d = nl & 63;
#pragma unroll
    for (int i = 0; i < 4; ++i) {
#pragma unroll
      for (int r = 0; r < 4; ++r) {
        const int m = m0 + wm + i * 16 + quad * 4 + r;
        const float v = (acc[i][j][r] + bn) * sc;
        const int t = m >> 2, bb = m & 3;  // m = t*B + b
        if (which < 2)
          outp[((size_t)(bb * H_ + hh) * T_ + t) * HD_ + d] = (f16)v;
        else
          outp[((size_t)(bb * H_ + hh) * HD_ + d) * T_ + t] = (f16)v;
      }
    }
  }
}

// ---------------------------------------------------------------- stage: attention
__device__ __forceinline__ void attn_stage(const MegaArgs& A, char* smem, int vt, int tid) {
  constexpr int SK = 128;
  constexpr int NT = T_ / SK;
  f16* Ks = (f16*)smem;               // 16KB
  f16* Vs = (f16*)(smem + 16384);     // 16KB
  f16* Psb = (f16*)smem;              // aliases Ks (dead during PV)
  const int wave = tid >> 6, lane = tid & 63;
  const int quad = lane >> 4, l16 = lane & 15;
  const int bh = vt & 63;             // same-XCD for all 8 q-blocks of a bh
  const int b = bh >> 4, h = bh & 15;
  const int q0 = (vt >> 6) * 128;
  const f16* Qbh = A.qb + ((size_t)bh * T_ + q0 + wave * 32) * HD_;
  const f16* Kbh = A.kb + (size_t)bh * T_ * HD_;
  const f16* Vbh = A.vb + (size_t)bh * HD_ * T_;

  f16x8 qf[2][2];
#pragma unroll
  for (int c = 0; c < 2; ++c) {
    qf[c][0] = *(const f16x8*)&Qbh[(c * 16 + l16) * HD_ + quad * 8];
    qf[c][1] = *(const f16x8*)&Qbh[(c * 16 + l16) * HD_ + 32 + quad * 8];
  }

  const f16* kq[4];
  const f16* vq[4];
  int lds_o[4];
#pragma unroll
  for (int it = 0; it < 4; ++it) {
    const int n = wave * 256 + it * 64 + lane;
    const int s = n >> 3, cp = n & 7, cl = cp ^ (s & 7);
    kq[it] = Kbh + (size_t)s * HD_ + cl * 8;
    const int d = n >> 4, cp2 = n & 15, cl2 = cp2 ^ (d & 7);
    vq[it] = Vbh + (size_t)d * T_ + cl2 * 8;
    lds_o[it] = (wave * 256 + it * 64) * 8;
  }

  f32x4 O[4][2] = {};
  float lsum[2] = {0.f, 0.f};
  const int sw = l16 & 7;

  for (int kt = 0; kt < NT; ++kt) {
    __syncthreads();  // prior-iteration readers (and Psb writers) done
#pragma unroll
    for (int it = 0; it < 4; ++it) {
      gl2lds16(kq[it], &Ks[lds_o[it]]);
      kq[it] += SK * HD_;
    }
#pragma unroll
    for (int it = 0; it < 4; ++it) {
      gl2lds16(vq[it], &Vs[lds_o[it]]);
      vq[it] += SK;
    }
    __syncthreads();  // staging complete

    float st[8][2][4];
#pragma unroll
    for (int s = 0; s < 8; ++s) {
      const int row = s * 16 + l16;
      const f16x8 ka = *(const f16x8*)&Ks[row * HD_ + (quad ^ sw) * 8];
      const f16x8 kb = *(const f16x8*)&Ks[row * HD_ + ((4 + quad) ^ sw) * 8];
#pragma unroll
      for (int c = 0; c < 2; ++c) {
        f32x4 a = {};
        a = __builtin_amdgcn_mfma_f32_16x16x32_f16(ka, qf[c][0], a, 0, 0, 0);
        a = __builtin_amdgcn_mfma_f32_16x16x32_f16(kb, qf[c][1], a, 0, 0, 0);
#pragma unroll
        for (int r = 0; r < 4; ++r) {
          st[s][c][r] = exp2f(a[r]);
          lsum[c] += st[s][c][r];
        }
      }
    }
    __syncthreads();  // all waves done reading Ks; Psb alias now safe

#pragma unroll
    for (int cI = 0; cI < 4; ++cI) {
#pragma unroll
      for (int c = 0; c < 2; ++c) {
        f16* pw = &Psb[wave * 16 * 36];
        f16x4 w0, w1;
#pragma unroll
        for (int r = 0; r < 4; ++r) {
          w0[r] = (f16)st[2 * cI][c][r];
          w1[r] = (f16)st[2 * cI + 1][c][r];
        }
        *(f16x4*)&pw[l16 * 36 + quad * 4] = w0;
        *(f16x4*)&pw[l16 * 36 + 16 + quad * 4] = w1;
        const f16x8 pf = *(const f16x8*)&pw[l16 * 36 + quad * 8];
#pragma unroll
        for (int dt = 0; dt < 4; ++dt) {
          const int d = dt * 16 + l16;
          const f16x8 vf = *(const f16x8*)&Vs[d * SK + (((cI * 4 + quad) ^ sw) * 8)];
          O[dt][c] = __builtin_amdgcn_mfma_f32_16x16x32_f16(vf, pf, O[dt][c], 0, 0, 0);
        }
      }
    }
  }

#pragma unroll
  for (int c = 0; c < 2; ++c) {
    float l = lsum[c];
    l += __shfl_xor(l, 16, 64);
    l += __shfl_xor(l, 32, 64);
    const float linv = 1.f / l;
    const int t = q0 + wave * 32 + c * 16 + l16;
#pragma unroll
    for (int dt = 0; dt < 4; ++dt) {
      f16x4 ov;
#pragma unroll
      for (int r = 0; r < 4; ++r) ov[r] = (f16)(O[dt][c][r] * linv);
      *(f16x4*)&A.ctxb[((size_t)t * B_ + b) * D_ + h * HD_ + dt * 16 + quad * 4] = ov;
    }
  }
}

// ---------------------------------------------------------------- stage: GEMM 128x64 (BK=32) + residual
__device__ __forceinline__ void gemm_stage(const f16* __restrict__ Ap,
                                           const f16* __restrict__ Wp,
                                           const float* __restrict__ bias,
                                           const f16* __restrict__ res,
                                           f16* __restrict__ out,
                                           char* smem, int vt, int tid) {
  constexpr int K = D_, BK = 32;
  f16* As = (f16*)smem;            // 8KB
  f16* Bs = (f16*)(smem + 8192);   // 4KB
  const int lane = tid & 63;
  const int quad = lane >> 4, l16 = lane & 15;
  const int m0 = (vt / 16) * 128, n0 = (vt % 16) * 64;
  const int wave = tid >> 6;
  const int wm = (wave >> 1) * 64, wn = (wave & 1) * 32;
  f32x4 acc[4][2] = {};
  for (int kt = 0; kt < K / BK; ++kt) {
    __syncthreads();
    const int kb = kt * BK;
#pragma unroll
    for (int i = 0; i < 2; ++i) {
      const int c = i * 256 + tid;
      const int row = c >> 2, col8 = (c & 3) * 8;
      const int ldsbase = (i * 256 + (tid & ~63)) * 8;
      gl2lds16(Ap + (size_t)(m0 + row) * K + kb + col8, &As[ldsbase]);
    }
    {
      const int row = tid >> 2, col8 = (tid & 3) * 8;
      const int ldsbase = (tid & ~63) * 8;
      gl2lds16(Wp + (size_t)(n0 + row) * K + kb + col8, &Bs[ldsbase]);
    }
    __syncthreads();
    f16x8 af[4], bf[2];
#pragma unroll
    for (int i = 0; i < 4; ++i)
      af[i] = *(const f16x8*)&As[(wm + i * 16 + l16) * BK + quad * 8];
#pragma unroll
    for (int j = 0; j < 2; ++j)
      bf[j] = *(const f16x8*)&Bs[(wn + j * 16 + l16) * BK + quad * 8];
#pragma unroll
    for (int i = 0; i < 4; ++i)
#pragma unroll
      for (int j = 0; j < 2; ++j)
        acc[i][j] = __builtin_amdgcn_mfma_f32_16x16x32_f16(af[i], bf[j], acc[i][j], 0, 0, 0);
  }
#pragma unroll
  for (int j = 0; j < 2; ++j) {
    const int n = n0 + wn + j * 16 + l16;
    const float bn = bias[n];
#pragma unroll
    for (int i = 0; i < 4; ++i) {
      const int m = m0 + wm + i * 16 + quad * 4;
#pragma unroll
      for (int r = 0; r < 4; ++r) {
        const float v = acc[i][j][r] + bn + (float)res[(size_t)(m + r) * D_ + n];
        out[(size_t)(m + r) * D_ + n] = (f16)v;
      }
    }
  }
}

// ---------------------------------------------------------------- stage: LayerNorm (one row)
__device__ __forceinline__ void lnorm_stage(const f16* __restrict__ a,
                                            const float* __restrict__ g,
                                            const float* __restrict__ bb,
                                            f16* __restrict__ outh,
                                            float* __restrict__ outf,
                                            char* smem, int row, int tid) {
  float* sc = (float*)smem;
  const size_t base = (size_t)row * D_;
  f16x4 va = *(const f16x4*)&a[base + tid * 4];
  float x0 = (float)va[0], x1 = (float)va[1], x2 = (float)va[2], x3 = (float)va[3];
  float s = x0 + x1 + x2 + x3;
  float sq = x0 * x0 + x1 * x1 + x2 * x2 + x3 * x3;
#pragma unroll
  for (int off = 32; off; off >>= 1) {
    s += __shfl_down(s, off, 64);
    sq += __shfl_down(sq, off, 64);
  }
  if ((tid & 63) == 0) { sc[tid >> 6] = s; sc[8 + (tid >> 6)] = sq; }
  __syncthreads();
  if (tid == 0) {
    float S = sc[0] + sc[1] + sc[2] + sc[3];
    float Qq = sc[8] + sc[9] + sc[10] + sc[11];
    float mean = S / D_;
    float var = Qq / D_ - mean * mean;
    sc[16] = mean;
    sc[17] = rsqrtf(var + 1e-5f);
  }
  __syncthreads();
  const float mean = sc[16], rstd = sc[17];
  __syncthreads();  // protect sc before next row's writes
  float4 vg = *(const float4*)&g[tid * 4];
  float4 vb = *(const float4*)&bb[tid * 4];
  float y0 = (x0 - mean) * rstd * vg.x + vb.x;
  float y1 = (x1 - mean) * rstd * vg.y + vb.y;
  float y2 = (x2 - mean) * rstd * vg.z + vb.z;
  float y3 = (x3 - mean) * rstd * vg.w + vb.w;
  if (outh) {
    f16x4 o = {(f16)y0, (f16)y1, (f16)y2, (f16)y3};
    *(f16x4*)&outh[base + tid * 4] = o;
  }
  if (outf)
    *(float4*)&outf[base + tid * 4] = make_float4(y0, y1, y2, y3);
}

// ---------------------------------------------------------------- mega kernel
__global__ __launch_bounds__(256, 2) void mega(MegaArgs A) {
  __shared__ __align__(16) char smem[32768];
  const int bid = blockIdx.x, tid = threadIdx.x;
  const int gtid = bid * 256 + tid;
  unsigned* cnt = A.bar;
  unsigned* gen = A.bar + 1;

  prep_stage(A, gtid);
  gbar(cnt, gen);

#pragma unroll 1
  for (int vt = bid; vt < 768; vt += NBLK) qkv_stage(A, smem, vt, tid);
  gbar(cnt, gen);

  attn_stage(A, smem, bid, tid);
  gbar(cnt, gen);

  gemm_stage(A.ctxb, A.wd[3], A.bo, A.xb, A.att, smem, bid, tid);  // Wo + x
  gbar(cnt, gen);

#pragma unroll 1
  for (int r = bid * 8; r < bid * 8 + 8; ++r)
    lnorm_stage(A.att, A.g1, A.b1, A.hbuf, nullptr, smem, r, tid);
  gbar(cnt, gen);

  gemm_stage(A.hbuf, A.wd[4], A.bl, A.hbuf, A.att, smem, bid, tid);  // Wl + h
  gbar(cnt, gen);

#pragma unroll 1
  for (int r = bid * 8; r < bid * 8 + 8; ++r)
    lnorm_stage(A.att, A.g2, A.b2, nullptr, A.out, smem, r, tid);
}

// ---------------------------------------------------------------- launch
extern "C" void kernel_launch(void* const* d_in, const int* in_sizes, int n_in,
                              void* d_out, int out_size, void* d_ws, size_t ws_size,
                              hipStream_t stream) {
  char* ws = (char*)d_ws;
  const size_t MB = 1 << 20;
  f16*   xb   = (f16*)(ws + 0 * MB);    // 8MB (stays alive as Wo residual)
  f16*   wqkv = (f16*)(ws + 8 * MB);    // 6MB
  f16*   wob  = (f16*)(ws + 14 * MB);   // 2MB
  f16*   wlb  = (f16*)(ws + 16 * MB);   // 2MB
  float* bqkv = (float*)(ws + 18 * MB); // 12KB
  f16*   qb   = (f16*)(ws + 19 * MB);   // 8MB -> att after attn
  f16*   kb   = (f16*)(ws + 27 * MB);   // 8MB -> hbuf after attn
  f16*   vb   = (f16*)(ws + 35 * MB);   // 8MB
  f16*   ctxb = (f16*)(ws + 43 * MB);   // 8MB
  unsigned* bar = (unsigned*)(ws + 51 * MB);

  MegaArgs ma;
  ma.x = (const float*)d_in[0];
  ma.w[0] = (const float*)d_in[1];   // Wq
  ma.b3[0] = (const float*)d_in[2];  // bq
  ma.w[1] = (const float*)d_in[3];   // Wk
  ma.b3[1] = (const float*)d_in[4];  // bk
  ma.w[2] = (const float*)d_in[5];   // Wv
  ma.b3[2] = (const float*)d_in[6];  // bv
  ma.w[3] = (const float*)d_in[7];   // Wo
  ma.bo = (const float*)d_in[8];
  ma.w[4] = (const float*)d_in[9];   // Wl
  ma.bl = (const float*)d_in[10];
  ma.g1 = (const float*)d_in[11];
  ma.b1 = (const float*)d_in[12];
  ma.g2 = (const float*)d_in[13];
  ma.b2 = (const float*)d_in[14];
  ma.xb = xb;
  ma.wd[0] = wqkv;
  ma.wd[1] = wqkv + D_ * D_;
  ma.wd[2] = wqkv + 2 * D_ * D_;
  ma.wd[3] = wob;
  ma.wd[4] = wlb;
  ma.bqkv = bqkv;
  ma.qb = qb; ma.kb = kb; ma.vb = vb; ma.ctxb = ctxb;
  ma.att = qb;    // qb dead after attn
  ma.hbuf = kb;   // kb dead after attn
  ma.out = (float*)d_out;
  ma.bar = bar;

  hipMemsetAsync(bar, 0, 128, stream);
  mega<<<NBLK, 256, 0, stream>>>(ma);
}